// Round 1
// baseline (133.019 us; speedup 1.0000x reference)
//
#include <hip/hip_runtime.h>

#define NSTEP 64
#define HDIM 1024
#define BDIM 2048

typedef float v2f __attribute__((ext_vector_type(2)));

__device__ __forceinline__ v2f vsplat(float s) { v2f r; r.x = s; r.y = s; return r; }

// Wave-level DPP lane shifts (single VALU op; proven exact in champion kernel).
// bound_ctrl=false: edge lane keeps own value; edge lanes are either identity
// rotations (s=0) or overwritten by the LDS cross-wave exchange below.
__device__ __forceinline__ float dpp_up1(float v) {   // lane n <- lane n-1
    int i = __builtin_bit_cast(int, v);
    int r = __builtin_amdgcn_update_dpp(i, i, 0x138, 0xF, 0xF, false);  // wave_shr:1
    return __builtin_bit_cast(float, r);
}
__device__ __forceinline__ float dpp_dn1(float v) {   // lane n <- lane n+1
    int i = __builtin_bit_cast(int, v);
    int r = __builtin_amdgcn_update_dpp(i, i, 0x130, 0xF, 0xF, false);  // wave_shl:1
    return __builtin_bit_cast(float, r);
}

// ---------------------------------------------------------------------------
// Kernel 1: coefficient tables, now in PLAIN (pair-ordered) layout:
//   etab[s*512 + p]        (c,s,sp,cp) for even pair p (cols 2p,2p+1)
//   otab[s*514 + 1 + j]    (c,s,sp,cp) for odd pair j (cols 2j+1,2j+2);
//                          index 0 and 512 are identity pads (j=-1, j=511)
//   wtab[c]                (cos w, sin w) per column
// Plain order => lane l of wave w reads contiguous 32/48 B at stride 32 B
// (coalesced), and this kernel's stores are coalesced too (old layout was a
// 1 KB-stride scatter).
// ---------------------------------------------------------------------------
__global__ void coeff_kernel(const float* __restrict__ omega,
                             const float* __restrict__ ETh,
                             const float* __restrict__ OTh,
                             const float* __restrict__ EPh,
                             const float* __restrict__ OPh,
                             float4* __restrict__ etab,
                             float4* __restrict__ otab,
                             float2* __restrict__ wtab)
{
    int idx = blockIdx.x * 256 + threadIdx.x;
    if (idx < NSTEP * 512) {
        float c, s, cp, sp;
        __sincosf(ETh[idx], &s, &c);
        __sincosf(EPh[idx], &sp, &cp);
        etab[idx] = make_float4(c, s, sp, cp);
    } else if (idx < 2 * NSTEP * 512) {
        int i2 = idx - NSTEP * 512;
        int st = i2 >> 9;
        int j  = i2 & 511;
        float4 v;
        if (j < 511) {
            float c, s, cp, sp;
            __sincosf(OTh[st * 511 + j], &s, &c);
            __sincosf(OPh[st * 511 + j], &sp, &cp);
            v = make_float4(c, s, sp, cp);
        } else {
            v = make_float4(1.f, 0.f, 1.f, 0.f);        // j=511 identity pad
        }
        otab[st * 514 + 1 + j] = v;
        if (j == 0) otab[st * 514] = make_float4(1.f, 0.f, 1.f, 0.f);  // j=-1 pad
    } else if (idx < 2 * NSTEP * 512 + HDIM) {
        int c = idx - 2 * NSTEP * 512;
        float cw, sw;
        __sincosf(omega[c], &sw, &cw);
        wtab[c] = make_float2(cw, sw);
    }
}

// Packed complex pair rotation: state A,B are (re,im) v2f; f = (c,sn,sp,cp).
//   t = c*A - sn*B;  B' = c*B + sn*A;  A' = (sp + i*cp) * t
__device__ __forceinline__ void pair_rot(const float4 f, v2f& A, v2f& B) {
    v2f C = vsplat(f.x), S = vsplat(f.y);
    v2f t = C * A - S * B;
    B = C * B + S * A;
    v2f cps; cps.x = -f.w; cps.y = f.w;
    A = vsplat(f.z) * t + cps * t.yx;
}
// Right-boundary variant: update A only, Bn is neighbor's value.
__device__ __forceinline__ void pair_rot_a(const float4 f, v2f& A, const v2f Bn) {
    v2f t = vsplat(f.x) * A - vsplat(f.y) * Bn;
    v2f cps; cps.x = -f.w; cps.y = f.w;
    A = vsplat(f.z) * t + cps * t.yx;
}

// ---------------------------------------------------------------------------
// Kernel 2: R=4 rows x c=4 cols-per-lane decomposition.
//   block = 256 threads = 4 waves; block owns 4 rows; wave w owns columns
//   [256w, 256w+255]; lane l owns cols 256w+4l .. +3 (4 complex = 8 VGPRs/row).
//   => 512 blocks, 2048 waves, 8 waves/CU = 2 waves/SIMD (was 1/SIMD), and
//   coefficient loads amortize over 4 rows: 5 dwordx4/wave/step (was 17 over
//   2 rows) -> L1 ~640 cyc/CU/step vs ~1088, SIMD ~600 cyc/CU/step. Balanced.
//   Intra-wave odd boundaries: DPP (as champion). Cross-wave boundaries (3 per
//   row-group): 256 B LDS, parity double-buffered, ONE raw s_barrier per step
//   with hand-placed lgkmcnt(0) -- NO vmcnt drain, so the one-step-ahead
//   coefficient prefetch stays in flight across the barrier.
// ---------------------------------------------------------------------------
__global__ __launch_bounds__(256, 2) void eunn_kernel(
    const float* __restrict__ x_re,
    const float* __restrict__ x_im,
    const float4* __restrict__ etab,
    const float4* __restrict__ otab,
    const float2* __restrict__ wtab,
    float* __restrict__ out)
{
    const int lane = threadIdx.x & 63;
    const int w    = threadIdx.x >> 6;          // H-quadrant 0..3
    const int row0 = blockIdx.x << 2;
    const int colbase = (w << 8) | (lane << 2); // 256w + 4l
    const int P = (w << 7) | (lane << 1);       // even-pair base = 128w + 2l

    // [parity][wave][side 0=col0,1=col3][rows01 | rows23] as float4 (re,im,re,im)
    __shared__ float4 ebuf[2][4][2][2];

    v2f x[4][4];   // [row][local col], interleaved (re, im)

    #pragma unroll
    for (int r = 0; r < 4; ++r) {
        float4 vr = *reinterpret_cast<const float4*>(x_re + (row0 + r) * HDIM + colbase);
        float4 vi = *reinterpret_cast<const float4*>(x_im + (row0 + r) * HDIM + colbase);
        x[r][0].x = vr.x; x[r][0].y = vi.x;
        x[r][1].x = vr.y; x[r][1].y = vi.y;
        x[r][2].x = vr.z; x[r][2].y = vi.z;
        x[r][3].x = vr.w; x[r][3].y = vi.w;
    }

    // step s, lane coefficients:
    //   e0: even pair P   (local cols 0,1)     e1: even pair P+1 (local 2,3)
    //   o0: odd pair P-1  (left cols -1,0; b-side)   [otab index P]
    //   o1: odd pair P    (local cols 1,2)           [otab index P+1]
    //   o2: odd pair P+1  (cols 3,4; a-side)         [otab index P+2]
    float4 ce0, ce1, co0, co1, co2;   // current step
    float4 ne0, ne1, no0, no1, no2;   // next step (prefetched)
    {
        const float4* e = etab + P;
        const float4* o = otab + P;
        ce0 = e[0]; ce1 = e[1];
        co0 = o[0]; co1 = o[1]; co2 = o[2];
    }

    auto step_body = [&](int par, float4 e0, float4 e1,
                         float4 o0, float4 o1, float4 o2) {
        // ---- even layer (all pairs intra-lane)
        #pragma unroll
        for (int r = 0; r < 4; ++r) {
            pair_rot(e0, x[r][0], x[r][1]);
            pair_rot(e1, x[r][2], x[r][3]);
        }

        // ---- cross-wave edge publish (post-even col0 / col3), 1 lane each
        if (lane == 0) {
            ebuf[par][w][0][0] = make_float4(x[0][0].x, x[0][0].y, x[1][0].x, x[1][0].y);
            ebuf[par][w][0][1] = make_float4(x[2][0].x, x[2][0].y, x[3][0].x, x[3][0].y);
        }
        if (lane == 63) {
            ebuf[par][w][1][0] = make_float4(x[0][3].x, x[0][3].y, x[1][3].x, x[1][3].y);
            ebuf[par][w][1][1] = make_float4(x[2][3].x, x[2][3].y, x[3][3].x, x[3][3].y);
        }

        // ---- intra-wave boundary exchange on post-even values via DPP
        v2f xn[4], xl[4];
        #pragma unroll
        for (int r = 0; r < 4; ++r) {
            xn[r].x = dpp_dn1(x[r][0].x);    // right neighbor lane's col0
            xn[r].y = dpp_dn1(x[r][0].y);
            xl[r].x = dpp_up1(x[r][3].x);    // left neighbor lane's col3
            xl[r].y = dpp_up1(x[r][3].y);
        }

        // Raw barrier: drain only LDS (edge writes), keep VMEM prefetch in flight.
        asm volatile("s_waitcnt lgkmcnt(0)" ::: "memory");
        __builtin_amdgcn_sched_barrier(0);
        __builtin_amdgcn_s_barrier();
        __builtin_amdgcn_sched_barrier(0);

        // ---- cross-wave edge consume (overrides DPP edge-lane values)
        if (lane == 63 && w < 3) {           // right neighbor wave's col0
            float4 a = ebuf[par][w + 1][0][0], b = ebuf[par][w + 1][0][1];
            xn[0].x = a.x; xn[0].y = a.y; xn[1].x = a.z; xn[1].y = a.w;
            xn[2].x = b.x; xn[2].y = b.y; xn[3].x = b.z; xn[3].y = b.w;
        }
        if (lane == 0 && w > 0) {            // left neighbor wave's col3
            float4 a = ebuf[par][w - 1][1][0], b = ebuf[par][w - 1][1][1];
            xl[0].x = a.x; xl[0].y = a.y; xl[1].x = a.z; xl[1].y = a.w;
            xl[2].x = b.x; xl[2].y = b.y; xl[3].x = b.z; xl[3].y = b.w;
        }
        // (w==3 lane63: o2 is identity pad, sn=0 -> xn irrelevant;
        //  w==0 lane0:  o0 is identity pad, sn=0 -> xl irrelevant)

        // ---- odd layer
        #pragma unroll
        for (int r = 0; r < 4; ++r) pair_rot(o1, x[r][1], x[r][2]);   // internal
        #pragma unroll
        for (int r = 0; r < 4; ++r) pair_rot_a(o2, x[r][3], xn[r]);   // right, a-side
        {
            v2f C = vsplat(o0.x), S = vsplat(o0.y);                   // left, b-side
            #pragma unroll
            for (int r = 0; r < 4; ++r) x[r][0] = C * x[r][0] + S * xl[r];
        }
    };

    // 2-step unrolled main loop: no coefficient register rotation movs;
    // each step's loads issued one full step before first use.
    for (int s = 0; s < NSTEP; s += 2) {
        {   // prefetch step s+1
            const float4* e = etab + (s + 1) * 512 + P;
            const float4* o = otab + (s + 1) * 514 + P;
            ne0 = e[0]; ne1 = e[1]; no0 = o[0]; no1 = o[1]; no2 = o[2];
        }
        step_body(0, ce0, ce1, co0, co1, co2);
        {   // prefetch step s+2 (clamped; last-iter loads are unused but valid)
            int s2 = (s + 2 < NSTEP) ? (s + 2) : (NSTEP - 1);
            const float4* e = etab + s2 * 512 + P;
            const float4* o = otab + s2 * 514 + P;
            ce0 = e[0]; ce1 = e[1]; co0 = o[0]; co1 = o[1]; co2 = o[2];
        }
        step_body(1, ne0, ne1, no0, no1, no2);
    }

    // ---- omega phase + de-interleave + store (coalesced float4)
    const float4* wp = reinterpret_cast<const float4*>(wtab + colbase);
    float4 wa = wp[0];   // (cw0,sw0,cw1,sw1) local cols 0,1
    float4 wb = wp[1];   // local cols 2,3
    #pragma unroll
    for (int r = 0; r < 4; ++r) {
        v2f X0 = x[r][0], X1 = x[r][1], X2 = x[r][2], X3 = x[r][3];
        float4 vr, vi;
        vr.x = X0.x * wa.x - X0.y * wa.y;  vi.x = X0.x * wa.y + X0.y * wa.x;
        vr.y = X1.x * wa.z - X1.y * wa.w;  vi.y = X1.x * wa.w + X1.y * wa.z;
        vr.z = X2.x * wb.x - X2.y * wb.y;  vi.z = X2.x * wb.y + X2.y * wb.x;
        vr.w = X3.x * wb.z - X3.y * wb.w;  vi.w = X3.x * wb.w + X3.y * wb.z;
        *reinterpret_cast<float4*>(out + (row0 + r) * HDIM + colbase) = vr;
        *reinterpret_cast<float4*>(out + BDIM * HDIM + (row0 + r) * HDIM + colbase) = vi;
    }
}

extern "C" void kernel_launch(void* const* d_in, const int* in_sizes, int n_in,
                              void* d_out, int out_size, void* d_ws, size_t ws_size,
                              hipStream_t stream)
{
    const float* x_re  = (const float*)d_in[0];
    const float* x_im  = (const float*)d_in[1];
    const float* omega = (const float*)d_in[2];
    const float* eth   = (const float*)d_in[3];
    const float* oth   = (const float*)d_in[4];
    const float* eph   = (const float*)d_in[5];
    const float* oph   = (const float*)d_in[6];

    char* ws = (char*)d_ws;
    float4* etab = (float4*)ws;                                  // 64*512*16 = 524288 B
    float4* otab = (float4*)(ws + NSTEP * 512 * 16);             // 64*514*16 = 526336 B
    float2* wtab = (float2*)(ws + NSTEP * 512 * 16 + NSTEP * 514 * 16);  // 8192 B

    coeff_kernel<<<260, 256, 0, stream>>>(omega, eth, oth, eph, oph, etab, otab, wtab);
    eunn_kernel<<<BDIM / 4, 256, 0, stream>>>(x_re, x_im, etab, otab, wtab, (float*)d_out);
}